// Round 8
// baseline (218.431 us; speedup 1.0000x reference)
//
#include <hip/hip_runtime.h>
#include <hip/hip_fp16.h>
#include <math.h>

#define NB 32
#define NL 512
#define NC 64
#define NG 3
#define NT 10000
#define NP 96
#define TOPM 20
#define M1 8      // per-lane per-chunk fp32 prefilter list
#define NCH 256   // t-chunks (250 real, 6 empty)
#define CHUNK 40
#define QK 16     // extracted per quarter (4 quarters -> 64 candidates)
#define NCAND 64
#define PNBLK 1250   // pnorm blocks (NT*NC/512)
#define TRBLK 5000   // transpose blocks (1250 t-tiles x 4 c-tiles)
#define GSTR ((size_t)NT * NC * 4)  // float stride between g-planes

// ---------------------------------------------------------------------------
// Kernel 1 (prep, 3 classes): [0,NB) qstat | [NB,NB+PNBLK) pnorm32 |
// [NB+PNBLK,..) y-transpose to fp16 yT[c][t][p]. Manual smem partition.
// ---------------------------------------------------------------------------
__global__ __launch_bounds__(512) void prep_kernel(
    const float* __restrict__ x, const float* __restrict__ ps,
    const float* __restrict__ y, double* __restrict__ q,
    float* __restrict__ phat, __half* __restrict__ yt16) {
  __shared__ __align__(16) char smem[50176];
  if (blockIdx.x < NB) {
    // ---- qstat (R5/R6/R7-proven math) ----
    double* s_sum = (double*)smem;        // [w][g][c] : w*192+g*64+c
    double* s_sq = s_sum + 1536;
    double* s_abs = s_sq + 1536;
    double* s_first = s_abs + 1536;       // [g][c]
    double* s_last = s_first + 192;
    const int b = blockIdx.x, w = threadIdx.x >> 6, c = threadIdx.x & 63;
    const float* xp = x + (size_t)b * NL * NC + c;
    const int l0 = w * 64;
    double sum[3] = {0, 0, 0}, sumsq[3] = {0, 0, 0}, sumabs[3] = {0, 0, 0};
    double prev[3] = {0, 0, 0}, first[3] = {0, 0, 0};
    if (w > 0) {
      double e0 = xp[(l0 - 4) * NC], e1 = xp[(l0 - 3) * NC];
      double e2 = xp[(l0 - 2) * NC], e3 = xp[(l0 - 1) * NC];
      prev[2] = e3; prev[1] = (e2 + e3) * 0.5; prev[0] = (e0 + e1 + e2 + e3) * 0.25;
    }
    double acc2 = 0.0, acc4 = 0.0;
    for (int i = 0; i < 64; ++i) {
      const int l = l0 + i;
      double v = (double)xp[l * NC];
      sum[2] += v; sumsq[2] += v * v;
      if (l == 0) first[2] = v; else sumabs[2] += fabs(v - prev[2]);
      prev[2] = v;
      acc2 += v;
      if (l & 1) {
        double cur = acc2 * 0.5; acc2 = 0.0;
        sum[1] += cur; sumsq[1] += cur * cur;
        if (l == 1) first[1] = cur; else sumabs[1] += fabs(cur - prev[1]);
        prev[1] = cur;
      }
      acc4 += v;
      if ((l & 3) == 3) {
        double cur = acc4 * 0.25; acc4 = 0.0;
        sum[0] += cur; sumsq[0] += cur * cur;
        if (l == 3) first[0] = cur; else sumabs[0] += fabs(cur - prev[0]);
        prev[0] = cur;
      }
    }
    for (int g = 0; g < 3; ++g) {
      s_sum[w * 192 + g * 64 + c] = sum[g];
      s_sq[w * 192 + g * 64 + c] = sumsq[g];
      s_abs[w * 192 + g * 64 + c] = sumabs[g];
    }
    if (w == 0) { for (int g = 0; g < 3; ++g) s_first[g * 64 + c] = first[g]; }
    if (w == 7) { for (int g = 0; g < 3; ++g) s_last[g * 64 + c] = prev[g]; }
    __syncthreads();
    if (w == 0) {
      const double J[3] = {128.0, 256.0, 512.0};
      for (int g = 0; g < 3; ++g) {
        double S = 0, Q2 = 0, A = 0;
        for (int ww = 0; ww < 8; ++ww) {
          S += s_sum[ww * 192 + g * 64 + c];
          Q2 += s_sq[ww * 192 + g * 64 + c];
          A += s_abs[ww * 192 + g * 64 + c];
        }
        double mean = S / J[g];
        double var = Q2 / J[g] - mean * mean; if (var < 0.0) var = 0.0;
        double last = s_last[g * 64 + c];
        double s0 = mean - last;
        double s1 = sqrt(var);
        double s2 = (last - s_first[g * 64 + c]) * (1.0 / 511.0);
        double s3 = A * (1.0 / 511.0);
        double n = sqrt(s0 * s0 + s1 * s1 + s2 * s2 + s3 * s3);
        double inv = 1.0 / fmax(n, 1e-12);
        double* qp = q + ((((size_t)g * NB) + b) * NC + c) * 4;
        qp[0] = s0 * inv; qp[1] = s1 * inv; qp[2] = s2 * inv; qp[3] = s3 * inv;
      }
    }
  } else if (blockIdx.x < NB + PNBLK) {
    // ---- pnorm32 (R6-proven) ----
    const int i = (blockIdx.x - NB) * 512 + threadIdx.x;  // over T*C
    if (i < NT * NC) {
      const int t = i >> 6, c = i & 63;
#pragma unroll
      for (int g = 0; g < 3; ++g) {
        const size_t off = ((((size_t)g * NT) + t) * NC + c) * 4;
        const float4 pv = *reinterpret_cast<const float4*>(ps + off);
        double p0 = pv.x, p1 = pv.y, p2 = pv.z, p3 = pv.w;
        double inv = 1.0 / fmax(sqrt(p0 * p0 + p1 * p1 + p2 * p2 + p3 * p3), 1e-12);
        float4 o;
        o.x = (float)(p0 * inv); o.y = (float)(p1 * inv);
        o.z = (float)(p2 * inv); o.w = (float)(p3 * inv);
        *reinterpret_cast<float4*>(phat + off) = o;
      }
    }
  } else {
    // ---- y transpose: yT16[c][t][p] = fp16(y[t][p][c]) ----
    float* lds = (float*)smem;  // [16][8][98] : c*784 + t*98 + p
    const int tb = blockIdx.x - NB - PNBLK;
    const int T0 = (tb % 1250) * 8;
    const int C0 = (tb / 1250) * 16;
    for (int i = threadIdx.x; i < 3072; i += 512) {  // 8t x 96p x 4cq
      const int cq = i & 3, p = (i >> 2) % 96, t = i / 384;
      const float4 v = *reinterpret_cast<const float4*>(
          y + ((size_t)(T0 + t) * NP + p) * NC + C0 + cq * 4);
      const int cb = cq * 4;
      lds[(cb + 0) * 784 + t * 98 + p] = v.x;
      lds[(cb + 1) * 784 + t * 98 + p] = v.y;
      lds[(cb + 2) * 784 + t * 98 + p] = v.z;
      lds[(cb + 3) * 784 + t * 98 + p] = v.w;
    }
    __syncthreads();
    for (int j = threadIdx.x; j < 6144; j += 512) {  // 16c x 8t x 48 half2
      const int p2 = j % 48, t = (j / 48) & 7, c = j / 384;
      const float a = lds[c * 784 + t * 98 + p2 * 2];
      const float bb = lds[c * 784 + t * 98 + p2 * 2 + 1];
      const __half2 h = __halves2half2(__float2half_rn(a), __float2half_rn(bb));
      *reinterpret_cast<__half2*>(
          yt16 + ((size_t)(C0 + c) * NT + T0 + t) * NP + p2 * 2) = h;
    }
  }
}

__device__ __forceinline__ void insert8(float s, int ti, float val[M1], int idx[M1]) {
  float cv = s; int ci = ti;
#pragma unroll
  for (int m = 0; m < M1; ++m) {
    bool sw = cv > val[m];
    float tv = sw ? val[m] : cv; int tx = sw ? idx[m] : ci;
    val[m] = sw ? cv : val[m];   idx[m] = sw ? ci : idx[m];
    cv = tv; ci = tx;
  }
}

// ---------------------------------------------------------------------------
// Kernel 2: fp32 prefilter scan (R6-proven verbatim). 1024-thr blocks = 16
// waves = 16 b's sharing one chunk stream; grid (2, NCH); LB(1024,8).
// ---------------------------------------------------------------------------
__global__ __launch_bounds__(1024, 8) void sim32_kernel(
    const float* __restrict__ phat, const double* __restrict__ q,
    float* __restrict__ cval, int* __restrict__ cidx) {
  const int wav = threadIdx.x >> 6;
  const int c = threadIdx.x & 63;
  const int b = blockIdx.x * 16 + wav;
  const int ch = blockIdx.y;
  float qv[12];
#pragma unroll
  for (int g = 0; g < 3; ++g) {
    const double* qp = q + ((((size_t)g * NB) + b) * NC + c) * 4;
#pragma unroll
    for (int j = 0; j < 4; ++j) qv[g * 4 + j] = (float)(qp[j] * (1.0 / 3.0));
  }
  float val[M1]; int idx[M1];
#pragma unroll
  for (int m = 0; m < M1; ++m) { val[m] = -1e30f; idx[m] = 0; }
  int t0 = ch * CHUNK;
  int t1 = t0 + CHUNK; if (t1 > NT) t1 = NT;
  for (int t = t0; t + 1 < t1; t += 2) {
    const size_t oA = ((size_t)t * NC + c) * 4;
    const size_t oB = oA + (size_t)NC * 4;
    const float4 a0 = *reinterpret_cast<const float4*>(phat + oA);
    const float4 a1 = *reinterpret_cast<const float4*>(phat + GSTR + oA);
    const float4 a2 = *reinterpret_cast<const float4*>(phat + 2 * GSTR + oA);
    const float4 b0 = *reinterpret_cast<const float4*>(phat + oB);
    const float4 b1 = *reinterpret_cast<const float4*>(phat + GSTR + oB);
    const float4 b2 = *reinterpret_cast<const float4*>(phat + 2 * GSTR + oB);
    float sA = qv[0] * a0.x + qv[1] * a0.y + qv[2] * a0.z + qv[3] * a0.w +
               qv[4] * a1.x + qv[5] * a1.y + qv[6] * a1.z + qv[7] * a1.w +
               qv[8] * a2.x + qv[9] * a2.y + qv[10] * a2.z + qv[11] * a2.w;
    float sB = qv[0] * b0.x + qv[1] * b0.y + qv[2] * b0.z + qv[3] * b0.w +
               qv[4] * b1.x + qv[5] * b1.y + qv[6] * b1.z + qv[7] * b1.w +
               qv[8] * b2.x + qv[9] * b2.y + qv[10] * b2.z + qv[11] * b2.w;
    if (sA > val[M1 - 1]) insert8(sA, t, val, idx);
    if (sB > val[M1 - 1]) insert8(sB, t + 1, val, idx);
  }
  float* vo = cval + ((((size_t)b * NC) + c) * NCH + ch) * M1;
  int* io = cidx + ((((size_t)b * NC) + c) * NCH + ch) * M1;
#pragma unroll
  for (int m = 0; m < M1; ++m) { vo[m] = val[m]; io[m] = idx[m]; }
}

// order-preserving fp32 -> u32 map; key = (v asc-map << 32) | (MAX - t)
// so u64-descending == (v desc, t asc). t unique per row => unique keys.
__device__ __forceinline__ unsigned long long mk_key(float v, int t) {
  unsigned u = __float_as_uint(v);
  u = (u & 0x80000000u) ? ~u : (u | 0x80000000u);
  return ((unsigned long long)u << 32) | (unsigned long long)(0xFFFFFFFFu - (unsigned)t);
}

// ---------------------------------------------------------------------------
// Kernel 3: merge + fp64 rerank (validated arithmetic) + softmax + COALESCED
// fp16 gather from yT16. Block = (c,b), 128 threads.
// ---------------------------------------------------------------------------
__global__ __launch_bounds__(128) void merge_gather_kernel(
    const float* __restrict__ cval, const int* __restrict__ cidx,
    const float* __restrict__ ps, const double* __restrict__ q,
    const __half* __restrict__ yt16, float* __restrict__ out) {
  const int c = blockIdx.x, b = blockIdx.y;
  __shared__ float v_s[NCH * M1];
  __shared__ int i_s[NCH * M1];
  __shared__ int ct_s[NCAND];
  __shared__ double rv_s[NCAND];
  __shared__ double m0_s, inv_s;
  __shared__ double e_s[TOPM];
  __shared__ int ts_s[TOPM];
  __shared__ float w_s[TOPM];
  const int n = NCH * M1;  // 2048
  const size_t row = (size_t)b * NC + c;
  const float4* vin = reinterpret_cast<const float4*>(cval + row * n);
  const int4* iin = reinterpret_cast<const int4*>(cidx + row * n);
  for (int k = threadIdx.x; k < n / 4; k += 128) {
    *reinterpret_cast<float4*>(&v_s[k * 4]) = vin[k];
    *reinterpret_cast<int4*>(&i_s[k * 4]) = iin[k];
  }
  __syncthreads();
  // --- quarter extraction: all 128 threads; quarter = (w<<1)|(lane>>5) ---
  {
    const int w = threadIdx.x >> 6, lane = threadIdx.x & 63;
    const int lane32 = lane & 31;
    const int qtr = (w << 1) | (lane >> 5);
    const int l0 = (qtr * 64 + lane32 * 2) * M1;
    const int l1 = l0 + M1;
    int p0 = 0, p1 = 0;
    unsigned long long k0 = mk_key(v_s[l0], i_s[l0]);
    unsigned long long k1 = mk_key(v_s[l1], i_s[l1]);
    for (int r = 0; r < QK; ++r) {
      unsigned long long me = k0 > k1 ? k0 : k1;
      unsigned long long km = me;
#pragma unroll
      for (int st = 1; st < 32; st <<= 1) {
        unsigned long long k2 = __shfl_xor(km, st);
        km = k2 > km ? k2 : km;
      }
      if (lane32 == r)
        ct_s[qtr * QK + r] = (int)(0xFFFFFFFFu - (unsigned)(km & 0xFFFFFFFFull));
      if (me == km) {  // unique keys -> exactly one owner
        if (k0 >= k1) {
          ++p0; k0 = (p0 < M1) ? mk_key(v_s[l0 + p0], i_s[l0 + p0]) : 0ull;
        } else {
          ++p1; k1 = (p1 < M1) ? mk_key(v_s[l1 + p1], i_s[l1 + p1]) : 0ull;
        }
      }
    }
  }
  __syncthreads();
  // --- fp64 re-score of 64 candidates (identical arithmetic to validated) ---
  double myv = -1e300; int myt = 0x7fffffff;
  if (threadIdx.x < NCAND) {
    myt = ct_s[threadIdx.x];
    double s = 0.0;
#pragma unroll
    for (int g = 0; g < 3; ++g) {
      const double* qp = q + ((((size_t)g * NB) + b) * NC + c) * 4;
      const float4 pv = *reinterpret_cast<const float4*>(
          ps + ((((size_t)g * NT) + myt) * NC + c) * 4);
      double pp0 = pv.x, pp1 = pv.y, pp2 = pv.z, pp3 = pv.w;
      double ss = pp0 * pp0 + pp1 * pp1 + pp2 * pp2 + pp3 * pp3;
      double dot = qp[0] * pp0 + qp[1] * pp1 + qp[2] * pp2 + qp[3] * pp3;
      s += dot / fmax(sqrt(ss), 1e-12);
    }
    myv = s * (1.0 / 3.0);
    rv_s[threadIdx.x] = myv;
  }
  __syncthreads();
  // --- rank by counting (v desc, t asc); ranks unique since t unique ---
  int rank = -1;
  if (threadIdx.x < NCAND) {
    rank = 0;
    for (int j = 0; j < NCAND; ++j) {
      double vj = rv_s[j]; int tj = ct_s[j];
      rank += (vj > myv) || (vj == myv && tj < myt);
    }
    if (rank == 0) m0_s = myv;
  }
  __syncthreads();
  if (rank >= 0 && rank < TOPM) { e_s[rank] = exp((myv - m0_s) * 10.0); ts_s[rank] = myt; }
  __syncthreads();
  if (threadIdx.x == 0) {
    double sum = 0.0;
#pragma unroll
    for (int m = 0; m < TOPM; ++m) sum += e_s[m];
    inv_s = 1.0 / sum;
  }
  __syncthreads();
  if (threadIdx.x < TOPM) w_s[threadIdx.x] = (float)(e_s[threadIdx.x] * inv_s);
  __syncthreads();
  // --- coalesced gather: lane p reads 20 contiguous 192B runs of yT16 ---
  const int p = threadIdx.x;
  if (p < NP) {
    const __half* yc = yt16 + (size_t)c * NT * NP + p;
    float acc = 0.f;
#pragma unroll
    for (int m = 0; m < TOPM; ++m)
      acc += w_s[m] * __half2float(yc[(size_t)ts_s[m] * NP]);
    out[(((size_t)b * NP) + p) * NC + c] = acc;
  }
}

// ---------------------------------------------------------------------------
// Fallback (small ws): round-1-proven all-fp64 inline path.
// ---------------------------------------------------------------------------
__global__ __launch_bounds__(256) void sim_topk_inline_kernel(
    const float* __restrict__ ps, const double* __restrict__ q,
    double* __restrict__ cval, int* __restrict__ cidx, int nch, int chunk) {
  const int wav = threadIdx.x >> 6;
  const int c = threadIdx.x & 63;
  const int b = blockIdx.y * 4 + wav;
  const int ch = blockIdx.x;
  double qv[3][4];
#pragma unroll
  for (int g = 0; g < 3; ++g) {
    const double* qp = q + ((((size_t)g * NB) + b) * NC + c) * 4;
    qv[g][0] = qp[0]; qv[g][1] = qp[1]; qv[g][2] = qp[2]; qv[g][3] = qp[3];
  }
  double val[TOPM]; int idx[TOPM];
#pragma unroll
  for (int m = 0; m < TOPM; ++m) { val[m] = -1e300; idx[m] = 0; }
  int t0 = ch * chunk;
  int t1 = t0 + chunk; if (t1 > NT) t1 = NT;
  for (int t = t0; t < t1; ++t) {
    double s = 0.0;
#pragma unroll
    for (int g = 0; g < 3; ++g) {
      const float4 pv = *reinterpret_cast<const float4*>(
          ps + ((((size_t)g * NT) + t) * NC + c) * 4);
      double p0 = pv.x, p1 = pv.y, p2 = pv.z, p3 = pv.w;
      double ss = p0 * p0 + p1 * p1 + p2 * p2 + p3 * p3;
      double dot = qv[g][0] * p0 + qv[g][1] * p1 + qv[g][2] * p2 + qv[g][3] * p3;
      s += dot / fmax(sqrt(ss), 1e-12);
    }
    s *= (1.0 / 3.0);
    if (s > val[TOPM - 1]) {
      double cv = s; int ci = t;
#pragma unroll
      for (int m = 0; m < TOPM; ++m) {
        bool sw = cv > val[m];
        double tv = sw ? val[m] : cv; int ti = sw ? idx[m] : ci;
        val[m] = sw ? cv : val[m];    idx[m] = sw ? ci : idx[m];
        cv = tv; ci = ti;
      }
    }
  }
  double* vout = cval + ((((size_t)b * NC) + c) * nch + ch) * TOPM;
  int* iout = cidx + ((((size_t)b * NC) + c) * nch + ch) * TOPM;
#pragma unroll
  for (int m = 0; m < TOPM; ++m) { vout[m] = val[m]; iout[m] = idx[m]; }
}

__global__ __launch_bounds__(128) void merge_gather_old_kernel(
    const double* __restrict__ cval, const int* __restrict__ cidx,
    const float* __restrict__ y, float* __restrict__ out, int nch) {
  const int c = blockIdx.x;
  const int b = blockIdx.y;
  __shared__ float w_s[TOPM];
  __shared__ int i_s[TOPM];
  if (threadIdx.x == 0) {
    double val[TOPM]; int idx[TOPM];
#pragma unroll
    for (int m = 0; m < TOPM; ++m) { val[m] = -1e300; idx[m] = 0; }
    const double* vin = cval + (((size_t)b * NC) + c) * nch * TOPM;
    const int* iin = cidx + (((size_t)b * NC) + c) * nch * TOPM;
    for (int k = 0; k < nch; ++k) {
      const int base = k * TOPM;
      for (int m = 0; m < TOPM; ++m) {
        double s = vin[base + m];
        if (!(s > val[TOPM - 1])) break;
        double cv = s; int ci = iin[base + m];
#pragma unroll
        for (int mm = 0; mm < TOPM; ++mm) {
          bool sw = cv > val[mm];
          double tv = sw ? val[mm] : cv; int ti = sw ? idx[mm] : ci;
          val[mm] = sw ? cv : val[mm];   idx[mm] = sw ? ci : idx[mm];
          cv = tv; ci = ti;
        }
      }
    }
    double mx = val[0];
    double e[TOPM]; double sum = 0.0;
#pragma unroll
    for (int m = 0; m < TOPM; ++m) { e[m] = exp((val[m] - mx) * 10.0); sum += e[m]; }
    double inv = 1.0 / sum;
#pragma unroll
    for (int m = 0; m < TOPM; ++m) { w_s[m] = (float)(e[m] * inv); i_s[m] = idx[m]; }
  }
  __syncthreads();
  const int p = threadIdx.x;
  if (p < NP) {
    float acc = 0.f;
#pragma unroll
    for (int m = 0; m < TOPM; ++m)
      acc += w_s[m] * y[(((size_t)i_s[m]) * NP + p) * NC + c];
    out[(((size_t)b * NP) + p) * NC + c] = acc;
  }
}

extern "C" void kernel_launch(void* const* d_in, const int* in_sizes, int n_in,
                              void* d_out, int out_size, void* d_ws, size_t ws_size,
                              hipStream_t stream) {
  const float* x = (const float*)d_in[0];
  const float* ps = (const float*)d_in[1];
  const float* y = (const float*)d_in[2];
  float* out = (float*)d_out;
  char* ws = (char*)d_ws;

  const size_t qbytes = (size_t)NG * NB * NC * 4 * sizeof(double);        // 196,608
  const size_t phatbytes = (size_t)NG * NT * NC * 4 * sizeof(float);      // 30.72 MB
  const size_t cvalbytes = (size_t)NB * NC * NCH * M1 * sizeof(float);    // 16.78 MB
  const size_t cidxbytes = (size_t)NB * NC * NCH * M1 * sizeof(int);      // 16.78 MB
  const size_t ytbytes = (size_t)NC * NT * NP * sizeof(__half);           // 122.88 MB

  double* qbuf = (double*)ws;

  if (ws_size >= qbytes + phatbytes + cvalbytes + cidxbytes + ytbytes) {
    float* phat = (float*)(ws + qbytes);
    float* cval = (float*)(ws + qbytes + phatbytes);
    int* cidx = (int*)((char*)cval + cvalbytes);
    __half* yt16 = (__half*)((char*)cidx + cidxbytes);
    prep_kernel<<<dim3(NB + PNBLK + TRBLK), dim3(512), 0, stream>>>(
        x, ps, y, qbuf, phat, yt16);
    sim32_kernel<<<dim3(NB / 16, NCH), dim3(1024), 0, stream>>>(phat, qbuf, cval, cidx);
    merge_gather_kernel<<<dim3(NC, NB), dim3(128), 0, stream>>>(cval, cidx, ps, qbuf,
                                                                yt16, out);
  } else {
    // fallback: round-1-proven all-fp64 path (prep runs qstat class only)
    prep_kernel<<<dim3(NB), dim3(512), 0, stream>>>(x, ps, y, qbuf,
                                                    (float*)nullptr, (__half*)nullptr);
    const size_t per_ch = (size_t)NB * NC * TOPM * (sizeof(double) + sizeof(int));
    int nch = 1;
    if (ws_size > qbytes) {
      size_t mc = (ws_size - qbytes) / per_ch;
      nch = mc < 32 ? (int)mc : 32;
      if (nch < 1) nch = 1;
    }
    const int chunk = (NT + nch - 1) / nch;
    double* cval = (double*)(ws + qbytes);
    int* cidx = (int*)((char*)cval + (size_t)NB * NC * nch * TOPM * sizeof(double));
    sim_topk_inline_kernel<<<dim3(nch, NB / 4), dim3(256), 0, stream>>>(
        ps, qbuf, cval, cidx, nch, chunk);
    merge_gather_old_kernel<<<dim3(NC, NB), dim3(128), 0, stream>>>(cval, cidx, y, out, nch);
  }
}